// Round 5
// baseline (197.834 us; speedup 1.0000x reference)
//
#include <hip/hip_runtime.h>
#include <hip/hip_bf16.h>

typedef __attribute__((ext_vector_type(8))) short short8;
typedef __attribute__((ext_vector_type(4))) float f32x4;

#define B_N 1024
#define D_K 512
#define C_N 100000
#define SCALE_F 64.0f
#define MARGIN_F 0.35f
#define BM 128
#define BN 128
#define BK 64
#define NT_ 782   // ceil(100000/128)
#define MT_ 8     // 1024/128
#define MAXL 64.0f   // global logit bound: |cos|*64 <= 64

__device__ __forceinline__ float dot4(float4 a, float4 b) {
    return a.x * b.x + a.y * b.y + a.z * b.z + a.w * b.w;
}

// round-to-nearest-even f32 -> bf16 bits
__device__ __forceinline__ ushort f2b(float f) {
    unsigned int u = __float_as_uint(f);
    u = (u + 0x7FFFu + ((u >> 16) & 1u)) >> 16;
    return (ushort)u;
}

// packed 2xf32 -> 2xbf16 (compiler emits v_cvt_pk_bf16_f32)
__device__ __forceinline__ unsigned int pk2(float a, float b) {
    float2 f2; f2.x = a; f2.y = b;
    __hip_bfloat162 t = __float22bfloat162_rn(f2);
    return *reinterpret_cast<unsigned int*>(&t);
}

// ---------------- kernel A: normalize x rows -> bf16 ----------------
__global__ void norm_x_kernel(const float* __restrict__ x,
                              ushort* __restrict__ xnb) {
    int row = blockIdx.x * 4 + (threadIdx.x >> 6);
    int l = threadIdx.x & 63;
    const float4* rp = (const float4*)(x + (size_t)row * D_K);
    float4 a = rp[l], b = rp[64 + l];
    float ssq = dot4(a, a) + dot4(b, b);
#pragma unroll
    for (int m = 1; m < 64; m <<= 1) ssq += __shfl_xor(ssq, m);
    float inv = 1.0f / fmaxf(sqrtf(ssq), 1e-12f);
    a.x *= inv; a.y *= inv; a.z *= inv; a.w *= inv;
    b.x *= inv; b.y *= inv; b.z *= inv; b.w *= inv;
    ushort4 ua; ua.x = f2b(a.x); ua.y = f2b(a.y); ua.z = f2b(a.z); ua.w = f2b(a.w);
    ushort4 ub; ub.x = f2b(b.x); ub.y = f2b(b.y); ub.z = f2b(b.z); ub.w = f2b(b.w);
    ushort4* obp = (ushort4*)(xnb + (size_t)row * D_K);
    obp[l] = ua; obp[64 + l] = ub;
}

// ------------- kernel B: disc loss partial + exact target logit -------------
__global__ void disc_kernel(const float* __restrict__ x,
                            const int* __restrict__ target,
                            const float* __restrict__ ida,
                            const float* __restrict__ bmat,
                            float* __restrict__ sums,
                            float* __restrict__ tlogit) {
    int row = blockIdx.x * 4 + (threadIdx.x >> 6);
    int l = threadIdx.x & 63;
    long t = (long)target[row];
    const float4* xp = (const float4*)(x + (size_t)row * D_K);
    const float4* wp = (const float4*)(ida + (size_t)t * D_K);
    const float4* bp = (const float4*)(bmat + (size_t)t * D_K);
    float4 x0 = xp[l], x1 = xp[64 + l];
    float4 w0 = wp[l], w1 = wp[64 + l];
    float4 b0 = bp[l], b1 = bp[64 + l];
    float xssq = dot4(x0, x0) + dot4(x1, x1);
    float wssq = dot4(w0, w0) + dot4(w1, w1);
    float bssq = dot4(b0, b0) + dot4(b1, b1);
#pragma unroll
    for (int m = 1; m < 64; m <<= 1) {
        xssq += __shfl_xor(xssq, m);
        wssq += __shfl_xor(wssq, m);
        bssq += __shfl_xor(bssq, m);
    }
    float xinv = 1.0f / fmaxf(sqrtf(xssq), 1e-12f);
    float winv = 1.0f / fmaxf(sqrtf(wssq), 1e-12f);
    float btn = sqrtf(bssq);
    float cs = fminf(btn, 0.05f) / fmaxf(btn, 1e-12f);

    float xs[8] = {x0.x, x0.y, x0.z, x0.w, x1.x, x1.y, x1.z, x1.w};
    float wv[8] = {w0.x, w0.y, w0.z, w0.w, w1.x, w1.y, w1.z, w1.w};
    float bv[8] = {b0.x, b0.y, b0.z, b0.w, b1.x, b1.y, b1.z, b1.w};
    float rss = 0.0f, dt = 0.0f;
#pragma unroll
    for (int i = 0; i < 8; ++i) {
        float xn = xs[i] * xinv;
        float wn = wv[i] * winv;
        float d = xn - wn;
        float r = d - bv[i] * cs;
        rss += r * r;
        dt += xn * wn;
    }
#pragma unroll
    for (int m = 1; m < 64; m <<= 1) {
        rss += __shfl_xor(rss, m);
        dt += __shfl_xor(dt, m);
    }
    if (l == 0) {
        atomicAdd(&sums[0], sqrtf(rss));
        tlogit[row] = SCALE_F * dt;
    }
}

// ------------- kernel C: bf16 MFMA GEMM with FUSED W-normalization -------------
// B-tile reg-staged from raw f32 id_agent: ssq accumulated in regs across K,
// packed to bf16 (cvt_pk), ds_written into XOR-swizzled slots (same involution
// as the MFMA read side). Per-column 64/||w|| applied in the fixed-max epilogue.
__global__ __launch_bounds__(256, 4) void gemm_lse_kernel(const ushort* __restrict__ A,
                                                          const float* __restrict__ Wf,
                                                          float* __restrict__ rowsum) {
    __shared__ ushort As[BM * BK];   // 16 KB, [row][8 slots of 16B], slots XOR-permuted
    __shared__ ushort Bs[BN * BK];   // 16 KB
    __shared__ float wssq_l[BN];
    __shared__ float rs[2][BM];

    int tid = threadIdx.x;
    int wave = tid >> 6, l = tid & 63;
    int wm = wave >> 1, wn = wave & 1;

    // XCD-bijective swizzle: xcd = bid % 8 gets a contiguous chunk of tile-space
    // ordered (nt major, mt minor) so 8 blocks sharing a W-tile share one L2.
    int tile = (blockIdx.x & 7) * NT_ + (blockIdx.x >> 3);
    int nt = tile >> 3, mt = tile & 7;
    int m0 = mt * BM, n0 = nt * BN;

    // A staging (global_load_lds, pre-swizzled source; unchanged from round 4)
    int srow = l >> 3;
    int scol = ((l & 7) ^ (l >> 3)) * 8;

    // B staging mapping: unit = i*256 + tid; row = i*32 + (tid>>3); slot = tid&7
    int tid8 = tid >> 3;
    int bls = tid & 7;
    int bps = bls ^ (tid8 & 7);          // physical slot = logical ^ (row&7)
    const float* bsrc[4];
    ushort* bdst[4];
#pragma unroll
    for (int i = 0; i < 4; ++i) {
        int rloc = i * 32 + tid8;
        int rg = n0 + rloc; if (rg > C_N - 1) rg = C_N - 1;
        bsrc[i] = Wf + (size_t)rg * D_K + bls * 8;
        bdst[i] = &Bs[rloc * BK + bps * 8];
    }
    float ssqp[4] = {0.0f, 0.0f, 0.0f, 0.0f};

    f32x4 zero4 = {0.0f, 0.0f, 0.0f, 0.0f};
    f32x4 acc[4][4];
#pragma unroll
    for (int i = 0; i < 4; ++i)
#pragma unroll
        for (int j = 0; j < 4; ++j) acc[i][j] = zero4;

    int cl = l & 15, hi = l >> 4;

    for (int kt = 0; kt < D_K; kt += BK) {
        // A -> LDS via async DMA
#pragma unroll
        for (int i = 0; i < 4; ++i) {
            int rb = wave * 32 + i * 8;
            const ushort* ga = A + (size_t)(m0 + rb + srow) * D_K + kt + scol;
            __builtin_amdgcn_global_load_lds(
                (const __attribute__((address_space(1))) void*)ga,
                (__attribute__((address_space(3))) void*)&As[rb * BK], 16, 0, 0);
        }
        // B: f32 -> regs (ssq) -> bf16 -> swizzled LDS
#pragma unroll
        for (int i = 0; i < 4; ++i) {
            float4 v0 = *(const float4*)(bsrc[i] + kt);
            float4 v1 = *(const float4*)(bsrc[i] + kt + 4);
            ssqp[i] += dot4(v0, v0) + dot4(v1, v1);
            uint4 hu;
            hu.x = pk2(v0.x, v0.y); hu.y = pk2(v0.z, v0.w);
            hu.z = pk2(v1.x, v1.y); hu.w = pk2(v1.z, v1.w);
            *(uint4*)bdst[i] = hu;
        }
        __syncthreads();

#pragma unroll
        for (int kk = 0; kk < 2; ++kk) {
            // physical slot = logical slot (kk*4+hi) XOR (row&7); row&7 == cl&7
            int px = (((kk << 2) | hi) ^ (cl & 7)) * 8;
            short8 af[4], bfr[4];
#pragma unroll
            for (int mi = 0; mi < 4; ++mi)
                af[mi] = *(const short8*)&As[(wm * 64 + mi * 16 + cl) * BK + px];
#pragma unroll
            for (int ni = 0; ni < 4; ++ni)
                bfr[ni] = *(const short8*)&Bs[(wn * 64 + ni * 16 + cl) * BK + px];
#pragma unroll
            for (int mi = 0; mi < 4; ++mi)
#pragma unroll
                for (int ni = 0; ni < 4; ++ni)
                    acc[mi][ni] = __builtin_amdgcn_mfma_f32_16x16x32_bf16(af[mi], bfr[ni], acc[mi][ni], 0, 0, 0);
        }
        __syncthreads();
    }

    // finalize per-row W ssq: reduce the 8 lanes (slots) sharing each row
#pragma unroll
    for (int i = 0; i < 4; ++i) {
        float s = ssqp[i];
        s += __shfl_xor(s, 1);
        s += __shfl_xor(s, 2);
        s += __shfl_xor(s, 4);
        if (bls == 0) wssq_l[i * 32 + tid8] = s;
    }
    __syncthreads();

    // per-lane column scales: 64 / ||w_col||
    float wiv[4];
#pragma unroll
    for (int ni = 0; ni < 4; ++ni) {
        float sq = wssq_l[wn * 64 + ni * 16 + cl];
        wiv[ni] = SCALE_F / fmaxf(sqrtf(sq), 1e-12f);
    }

    // epilogue: per-row sum of exp(s - 64); logits are cosines*64 so s <= 64(+eps)
#pragma unroll
    for (int mi = 0; mi < 4; ++mi) {
#pragma unroll
        for (int j = 0; j < 4; ++j) {
            float se = 0.0f;
#pragma unroll
            for (int ni = 0; ni < 4; ++ni) {
                int cg = n0 + wn * 64 + ni * 16 + cl;
                if (cg < C_N) se += __expf(acc[mi][ni][j] * wiv[ni] - MAXL);
            }
#pragma unroll
            for (int xm = 1; xm < 16; xm <<= 1) se += __shfl_xor(se, xm);
            if (cl == 0) rs[wn][wm * 64 + mi * 16 + hi * 4 + j] = se;
        }
    }
    __syncthreads();
    if (tid < BM) {
        float s = rs[0][tid] + rs[1][tid];
        atomicAdd(&rowsum[m0 + tid], s);
    }
}

// ------------- kernel D: per-row lse from fixed-max sumexp -> nll -> sums[1] -------------
__global__ void rowfin_kernel(const float* __restrict__ rowsum,
                              const float* __restrict__ tlogit,
                              float* __restrict__ sums) {
    __shared__ float red[4];
    int tid = threadIdx.x;
    int row = blockIdx.x * 256 + tid;
    float lse = MAXL + logf(rowsum[row]);
    float st = tlogit[row];
    // replace exp(st) by exp(st - 64*margin) inside the lse
    float corr = __expf(st - lse) * (__expf(-SCALE_F * MARGIN_F) - 1.0f);
    float lse2 = lse + log1pf(corr);
    float nll = lse2 - (st - SCALE_F * MARGIN_F);
#pragma unroll
    for (int xm = 1; xm < 64; xm <<= 1) nll += __shfl_xor(nll, xm);
    if ((tid & 63) == 0) red[tid >> 6] = nll;
    __syncthreads();
    if (tid == 0) atomicAdd(&sums[1], red[0] + red[1] + red[2] + red[3]);
}

// ------------- kernel E: finalize scalar output -------------
__global__ void finalize_kernel(const float* __restrict__ sums, float* __restrict__ out) {
    float disc = sums[0] * (1.0f / B_N);
    float logp = sums[1] * (1.0f / B_N);
    float p = __expf(-logp);
    float om = 1.0f - p;
    out[0] = 0.4f * disc + om * om * logp;
}

extern "C" void kernel_launch(void* const* d_in, const int* in_sizes, int n_in,
                              void* d_out, int out_size, void* d_ws, size_t ws_size,
                              hipStream_t stream) {
    const float* x = (const float*)d_in[0];
    const int* target = (const int*)d_in[1];
    const float* ida = (const float*)d_in[2];
    const float* bmat = (const float*)d_in[3];
    float* out = (float*)d_out;

    char* ws = (char*)d_ws;
    size_t off = 0;
    float* rowsum = (float*)(ws + off);  off += (size_t)B_N * 4;         // 4 KB
    float* sums = (float*)(ws + off);    off += 256;
    ushort* xnb = (ushort*)(ws + off);   off += (size_t)B_N * D_K * 2;   // 1 MB
    float* tlogit = (float*)(ws + off);  off += (size_t)B_N * 4;

    // zero rowsum + sums (contiguous region) every call — deterministic
    hipMemsetAsync(rowsum, 0, (size_t)B_N * 4 + 256, stream);

    norm_x_kernel<<<B_N / 4, 256, 0, stream>>>(x, xnb);
    disc_kernel<<<B_N / 4, 256, 0, stream>>>(x, target, ida, bmat, sums, tlogit);
    gemm_lse_kernel<<<MT_ * NT_, 256, 0, stream>>>(xnb, ida, rowsum);
    rowfin_kernel<<<B_N / 256, 256, 0, stream>>>(rowsum, tlogit, sums);
    finalize_kernel<<<1, 1, 0, stream>>>(sums, out);
}